// Round 7
// baseline (5215.728 us; speedup 1.0000x reference)
//
#include <hip/hip_runtime.h>
#include <stdint.h>

// ---------------- problem constants ----------------
#define T_STEPS 1000
#define B_SZ    32
#define NI      512
#define NH      1024
#define NO      256

#define NSLICE  8     // neuron slices per batch; block (b,s) owns 128 neurons of batch b
#define NBLK    (B_SZ * NSLICE)   // 256 scan blocks
#define SEG     136   // slist entries per chunk segment (stride de-banks LDS writes)

typedef unsigned long long u64;

// ---------------- ws layout (bytes) ----------------
#define OFF_IEXT 0ull
#define SZ_IEXT  ((unsigned long long)T_STEPS * B_SZ * NH * 4ull)   // 131,072,000
#define OFF_WTS  (OFF_IEXT + SZ_IEXT)
#define SZ_WTS   ((unsigned long long)NH * NH * 4ull)               // 4 MiB, WTS[s][i][jj]
#define OFF_RATE (OFF_WTS + SZ_WTS)
#define SZ_RATE  ((unsigned long long)B_SZ * NH * 4ull)             // 128 KiB
#define OFF_SYNC (OFF_RATE + SZ_RATE)
#define SZ_SYNC  ((unsigned long long)2 * B_SZ * NSLICE * 4 * 8ull) // 16 KiB

// ---------------- scope helpers ----------------
__device__ __forceinline__ u64 ld64_agent(const u64* p) {
  return __hip_atomic_load(p, __ATOMIC_RELAXED, __HIP_MEMORY_SCOPE_AGENT);
}
__device__ __forceinline__ void st64_agent(u64* p, u64 v) {
  __hip_atomic_store(p, v, __ATOMIC_RELAXED, __HIP_MEMORY_SCOPE_AGENT);
}
__device__ __forceinline__ int ld_acq(const int* p) {
  return __hip_atomic_load(p, __ATOMIC_ACQUIRE, __HIP_MEMORY_SCOPE_WORKGROUP);
}
__device__ __forceinline__ void st_rel(int* p, int v) {
  __hip_atomic_store(p, v, __ATOMIC_RELEASE, __HIP_MEMORY_SCOPE_WORKGROUP);
}

// ---------------- kernel 1: transpose W_rec -> WTS ----------------
// WTS[(s*1024 + i)*128 + jj] = W_rec[(128s+jj)*1024 + i]   (verified R5/R6)
__global__ __launch_bounds__(256) void prep_wts(const float* __restrict__ Wrec,
                                                float* __restrict__ WTS) {
  __shared__ float tile[64][65];
  const int tid = threadIdx.x;
  const int j0 = blockIdx.x * 64;
  const int i0 = blockIdx.y * 64;
  const int sl = j0 >> 7;
  const int jjb = j0 & 127;
#pragma unroll
  for (int k = 0; k < 16; ++k) {
    const int idx = k * 256 + tid;
    const int jl = idx >> 6, il = idx & 63;
    tile[jl][il] = Wrec[(size_t)(j0 + jl) * NH + i0 + il];
  }
  __syncthreads();
#pragma unroll
  for (int k = 0; k < 16; ++k) {
    const int idx = k * 256 + tid;
    const int il = idx >> 6, jl = idx & 63;
    WTS[((size_t)(sl * NH + i0 + il)) * 128 + jjb + jl] = tile[jl][il];
  }
}

// ---------------- kernel 2: I_ext = x @ W_in^T  (fp32 tiled) ----------------
// Kept fp32: bf16 I_ext would flip threshold crossings and cascade.
#define GBM 128
#define GBN 128
#define GBK 16
__global__ __launch_bounds__(256) void gemm_in(const float* __restrict__ X,
                                               const float* __restrict__ Win,
                                               float* __restrict__ I) {
  __shared__ float As[GBK][GBM + 4];
  __shared__ float Bs[GBK][GBN + 4];
  const int tid = threadIdx.x;
  const int m0 = blockIdx.x * GBM;
  const int n0 = blockIdx.y * GBN;
  const int tm = tid >> 4, tn = tid & 15;
  const int lr = tid >> 1, lk = (tid & 1) * 8;
  float acc[8][8] = {};
  for (int k0 = 0; k0 < NI; k0 += GBK) {
    float4 a0 = *(const float4*)&X[(size_t)(m0 + lr) * NI + k0 + lk];
    float4 a1 = *(const float4*)&X[(size_t)(m0 + lr) * NI + k0 + lk + 4];
    float4 b0 = *(const float4*)&Win[(size_t)(n0 + lr) * NI + k0 + lk];
    float4 b1 = *(const float4*)&Win[(size_t)(n0 + lr) * NI + k0 + lk + 4];
    As[lk + 0][lr] = a0.x; As[lk + 1][lr] = a0.y; As[lk + 2][lr] = a0.z; As[lk + 3][lr] = a0.w;
    As[lk + 4][lr] = a1.x; As[lk + 5][lr] = a1.y; As[lk + 6][lr] = a1.z; As[lk + 7][lr] = a1.w;
    Bs[lk + 0][lr] = b0.x; Bs[lk + 1][lr] = b0.y; Bs[lk + 2][lr] = b0.z; Bs[lk + 3][lr] = b0.w;
    Bs[lk + 4][lr] = b1.x; Bs[lk + 5][lr] = b1.y; Bs[lk + 6][lr] = b1.z; Bs[lk + 7][lr] = b1.w;
    __syncthreads();
#pragma unroll
    for (int k = 0; k < GBK; ++k) {
      float av[8], bv[8];
      *(float4*)&av[0] = *(const float4*)&As[k][tm * 8];
      *(float4*)&av[4] = *(const float4*)&As[k][tm * 8 + 4];
      *(float4*)&bv[0] = *(const float4*)&Bs[k][tn * 8];
      *(float4*)&bv[4] = *(const float4*)&Bs[k][tn * 8 + 4];
#pragma unroll
      for (int i2 = 0; i2 < 8; ++i2)
#pragma unroll
        for (int j2 = 0; j2 < 8; ++j2) acc[i2][j2] += av[i2] * bv[j2];
    }
    __syncthreads();
  }
#pragma unroll
  for (int i2 = 0; i2 < 8; ++i2) {
    float4 c0 = {acc[i2][0], acc[i2][1], acc[i2][2], acc[i2][3]};
    float4 c1 = {acc[i2][4], acc[i2][5], acc[i2][6], acc[i2][7]};
    *(float4*)&I[(size_t)(m0 + tm * 8 + i2) * NH + n0 + tn * 8] = c0;
    *(float4*)&I[(size_t)(m0 + tm * 8 + i2) * NH + n0 + tn * 8 + 4] = c1;
  }
}

// ---------------- kernel 3: persistent scan, pipelined sync, no in-loop barriers ----
// Block (b,sl): 320 threads / 5 waves.
//   waves 0,1 (tid 0-127): neuron state (1/lane) + publish + A-half gather
//                          (chunks 0-3) + reduce/h/psc.
//   waves 2,3 (tid 128-255): B-half gather (chunks 4-7), psumB, epoch release.
//   wave 4 (lanes 0-7):    per-chunk poller/compactor. Lane q polls producer
//                          q's 4 tagged words; on arrival expands them into
//                          slist segment q (parity-buffered) and RELEASES
//                          flagq[q] = (t+1)<<8 | cnt. Gather waves consume
//                          chunks in ascending q via acquire spins -> early
//                          chunks are gathered while late producers are still
//                          in flight; only the last chunk sits on the chain.
// FP order identical to R6: per half, chunk-ascending / word-ascending /
// bit-ascending; zero-padded MLP batches add +0.0f only; rec = sA + psumB.
// Overwrite safety: slist parity double-buffer; flagq/ep monotone. flagq can
// never skip past want while a gatherer spins: advancing to t+2 requires this
// block's publish(t+2) <- reduce(t+1) <- ep(t+1) <- waves2,3 passed t+1 spins.
__global__ __launch_bounds__(320) void scan_rsnn(const float* __restrict__ Iext,
                                                 const float* __restrict__ WTS,
                                                 float* __restrict__ rate,
                                                 u64* sync) {
  __shared__ unsigned short slist[2 * 8 * SEG + 16];  // parity x 8 chunks x SEG
  __shared__ int flagq[8];                            // (epoch<<8) | cnt
  __shared__ int ep2, ep3;                            // psumB epochs (wave2 / wave3)
  __shared__ float psumB[128];

  const int bid = blockIdx.x;
  const int b   = bid >> 3;
  const int sl  = bid & 7;
  const int tid = threadIdx.x;
  const int wv  = tid >> 6;
  const int ln  = tid & 63;

  const float* wts = WTS + (size_t)sl * NH * 128;

  const float D1 = 0.90483741803595957f;    // exp(-0.1)
  const float D2 = 0.81873075307798186f;    // exp(-0.2) == decay_syn

  if (tid < 8) flagq[tid] = 0;
  if (tid == 8) ep2 = 0;
  if (tid == 9) ep3 = 0;
  __syncthreads();                          // once, outside the loop

  float v = -60.0f, A1 = 0.0f, A2 = 0.0f, rf = 0.0f, h = 0.0f, psc = 0.0f;
  float ip = 0.0f;
  int sc = 0;
  if (tid < 128) ip = Iext[(size_t)b * NH + sl * 128 + tid];

  for (int t = 0; t < T_STEPS; ++t) {
    const int par = t & 1;
    const int want = t + 1;
    u64* gbase = sync + ((size_t)(par * B_SZ + b)) * (NSLICE * 4);

    if (wv < 2) {
      // ---- state update (op order matches reference; publish before bookkeeping)
      const float I = ip + psc;
      A1 *= D1; A2 *= D2;
      v = v + ((-60.0f - v) / 20.0f + (I + A1 + A2) / 2.0f);
      const bool inref = rf > 0.0f;
      if (inref) v = -60.0f;
      const bool spike = (!inref) && (v >= -45.0f);
      const u64 bal = __ballot(spike);
      if (ln < 2) {
        const int w = wv * 2 + ln;          // word layout identical to R5/R6
        const unsigned payload = ln ? (unsigned)(bal >> 32) : (unsigned)bal;
        st64_agent(&gbase[sl * 4 + w], (u64)payload | ((u64)(unsigned)want << 32));
      }
      if (spike) { v = -60.0f; A1 += 1.0f; A2 += -2.0f; rf = 2.0f; sc++; }
      else       { rf = fmaxf(rf - 1.0f, 0.0f); }
      __builtin_amdgcn_sched_barrier(0);    // keep prefetch below the publish
      const int tn2 = (t + 1 < T_STEPS) ? t + 1 : t;
      ip = Iext[((size_t)tn2 * B_SZ + b) * NH + sl * 128 + tid];

      // ---- A-half gather: chunks 0..3 in order, as they are released
      float s = 0.0f;
#pragma unroll
      for (int q2 = 0; q2 < 4; ++q2) {
        int fv = ld_acq(&flagq[q2]);
        while ((fv >> 8) < want) fv = ld_acq(&flagq[q2]);
        const int cnt = fv & 255;
        const unsigned short* sp = &slist[par * (8 * SEG) + q2 * SEG];
        for (int k = 0; k < cnt; k += 16) {
          float w16[16];
#pragma unroll
          for (int m2 = 0; m2 < 16; ++m2) {
            const int kk = k + m2;
            const int kk2 = (kk < cnt) ? kk : 0;
            const float val = wts[(size_t)sp[kk2] * 128 + tid];
            w16[m2] = (kk < cnt) ? val : 0.0f;
          }
#pragma unroll
          for (int m2 = 0; m2 < 16; ++m2) s += w16[m2];   // in-order adds
        }
      }
      // ---- reduce: wait for my half's psumB epoch, then h/psc update
      if (wv == 0) { while (ld_acq(&ep2) < want) {} }
      else         { while (ld_acq(&ep3) < want) {} }
      const float rec = s + psumB[tid];     // same A+B association as R2-R6
      h = D2 * h + rec;
      psc = D2 * psc + h;
    } else if (wv < 4) {
      // ---- B-half gather: chunks 4..7, jl = tid-128
      const int jl = tid - 128;
      float s = 0.0f;
#pragma unroll
      for (int q2 = 4; q2 < 8; ++q2) {
        int fv = ld_acq(&flagq[q2]);
        while ((fv >> 8) < want) fv = ld_acq(&flagq[q2]);
        const int cnt = fv & 255;
        const unsigned short* sp = &slist[par * (8 * SEG) + q2 * SEG];
        for (int k = 0; k < cnt; k += 16) {
          float w16[16];
#pragma unroll
          for (int m2 = 0; m2 < 16; ++m2) {
            const int kk = k + m2;
            const int kk2 = (kk < cnt) ? kk : 0;
            const float val = wts[(size_t)sp[kk2] * 128 + jl];
            w16[m2] = (kk < cnt) ? val : 0.0f;
          }
#pragma unroll
          for (int m2 = 0; m2 < 16; ++m2) s += w16[m2];
        }
      }
      psumB[jl] = s;
      if (tid == 128) st_rel(&ep2, want);   // release orders the wave's LDS writes
      if (tid == 192) st_rel(&ep3, want);
    } else {
      // ---- wave 4: incremental poll + compact, lane q <-> producer chunk q
      unsigned pend = (ln < 8) ? 1u : 0u;
      const int q = ln & 7;
      const u64* gp = &gbase[q * 4];
      while (__ballot(pend)) {
        u64 a0 = 0, a1 = 0, a2 = 0, a3 = 0;
        if (pend) {
          a0 = ld64_agent(gp + 0); a1 = ld64_agent(gp + 1);
          a2 = ld64_agent(gp + 2); a3 = ld64_agent(gp + 3);
        }
        const unsigned uw = (unsigned)want;
        const bool fresh = pend &&
            ((unsigned)(a0 >> 32) == uw) && ((unsigned)(a1 >> 32) == uw) &&
            ((unsigned)(a2 >> 32) == uw) && ((unsigned)(a3 >> 32) == uw);
        if (fresh) {
          unsigned short* sp = &slist[par * (8 * SEG) + q * SEG];
          int off = 0;
          unsigned wsx[4] = {(unsigned)a0, (unsigned)a1, (unsigned)a2, (unsigned)a3};
#pragma unroll
          for (int w2 = 0; w2 < 4; ++w2) {
            unsigned m = wsx[w2];
            const int basei = q * 128 + w2 * 32;
            while (m) {
              const int bit = __builtin_ctz(m);
              m &= m - 1;
              sp[off++] = (unsigned short)(basei + bit);
            }
          }
          st_rel(&flagq[q], (want << 8) | off);   // data precedes flag
          pend = 0;
        }
      }
    }
  }

  if (tid < 128) rate[(size_t)b * NH + sl * 128 + tid] = (float)sc / 1000.0f;
}

// ---------------- kernel 4: out = rate @ W_out^T ----------------
__global__ __launch_bounds__(256) void out_gemv(const float* __restrict__ rate,
                                                const float* __restrict__ Wout,
                                                float* __restrict__ out) {
  __shared__ float rs[NH];
  const int b = blockIdx.x, tid = threadIdx.x;
  for (int i = tid; i < NH; i += 256) rs[i] = rate[(size_t)b * NH + i];
  __syncthreads();
  const float* wr = Wout + (size_t)tid * NH;
  float s = 0.0f;
  for (int hh = 0; hh < NH; hh += 4) {
    float4 w4 = *(const float4*)&wr[hh];
    s += rs[hh] * w4.x + rs[hh + 1] * w4.y + rs[hh + 2] * w4.z + rs[hh + 3] * w4.w;
  }
  out[(size_t)b * NO + tid] = s;
}

// ---------------- launch ----------------
extern "C" void kernel_launch(void* const* d_in, const int* in_sizes, int n_in,
                              void* d_out, int out_size, void* d_ws, size_t ws_size,
                              hipStream_t stream) {
  const float* x    = (const float*)d_in[0];
  const float* Win  = (const float*)d_in[1];
  const float* Wrec = (const float*)d_in[2];
  const float* Wout = (const float*)d_in[3];
  float* out = (float*)d_out;

  char* ws = (char*)d_ws;
  float* Iext = (float*)(ws + OFF_IEXT);
  float* WTS  = (float*)(ws + OFF_WTS);
  float* rate = (float*)(ws + OFF_RATE);
  u64*   sync = (u64*)(ws + OFF_SYNC);
  // No memset needed: 0xAA poison tag (0xAAAAAAAA) never equals t+1 <= 1000,
  // and every block publishes before any of its spins -> no deadlock.

  prep_wts<<<dim3(16, 16), dim3(256), 0, stream>>>(Wrec, WTS);
  gemm_in<<<dim3((T_STEPS * B_SZ) / GBM, NH / GBN), dim3(256), 0, stream>>>(x, Win, Iext);
  scan_rsnn<<<dim3(NBLK), dim3(320), 0, stream>>>(Iext, WTS, rate, sync);
  out_gemv<<<dim3(B_SZ), dim3(256), 0, stream>>>(rate, Wout, out);
}

// Round 8
// 4196.823 us; speedup vs baseline: 1.2428x; 1.2428x over previous
//
#include <hip/hip_runtime.h>
#include <stdint.h>

// ---------------- problem constants ----------------
#define T_STEPS 1000
#define B_SZ    32
#define NI      512
#define NH      1024
#define NO      256

#define NSLICE  8     // neuron slices per batch; block (b,s) owns 128 neurons of batch b
#define NBLK    (B_SZ * NSLICE)   // 256 scan blocks
#define SEG     136   // slist entries per chunk segment (16B-aligned stride)
#define ZROW    1024  // per-slice zero row index (pad entries add +0.0f)
#define SLICE_STRIDE ((NH + 1) * 128)   // 131200 floats per slice incl. zero row

typedef unsigned long long u64;

// ---------------- ws layout (bytes) ----------------
#define OFF_IEXT 0ull
#define SZ_IEXT  ((unsigned long long)T_STEPS * B_SZ * NH * 4ull)   // 131,072,000
#define OFF_WTS  (OFF_IEXT + SZ_IEXT)
#define SZ_WTS   ((unsigned long long)NSLICE * SLICE_STRIDE * 4ull) // 4,198,400
#define OFF_RATE (OFF_WTS + SZ_WTS)
#define SZ_RATE  ((unsigned long long)B_SZ * NH * 4ull)             // 128 KiB
#define OFF_SYNC (OFF_RATE + SZ_RATE)
#define SZ_SYNC  ((unsigned long long)2 * B_SZ * NSLICE * 4 * 8ull) // 16 KiB

// ---------------- scope helpers ----------------
__device__ __forceinline__ u64 ld64_agent(const u64* p) {
  return __hip_atomic_load(p, __ATOMIC_RELAXED, __HIP_MEMORY_SCOPE_AGENT);
}
__device__ __forceinline__ void st64_agent(u64* p, u64 v) {
  __hip_atomic_store(p, v, __ATOMIC_RELAXED, __HIP_MEMORY_SCOPE_AGENT);
}
__device__ __forceinline__ int ld_acq(const int* p) {
  return __hip_atomic_load(p, __ATOMIC_ACQUIRE, __HIP_MEMORY_SCOPE_WORKGROUP);
}
__device__ __forceinline__ void st_rel(int* p, int v) {
  __hip_atomic_store(p, v, __ATOMIC_RELEASE, __HIP_MEMORY_SCOPE_WORKGROUP);
}

// ---------------- kernel 1: transpose W_rec -> WTS (+ zero pad row) ------------
// WTS[sl*SLICE_STRIDE + i*128 + jj] = W_rec[(128sl+jj)*1024 + i]; row ZROW = 0.
__global__ __launch_bounds__(256) void prep_wts(const float* __restrict__ Wrec,
                                                float* __restrict__ WTS) {
  __shared__ float tile[64][65];
  const int tid = threadIdx.x;
  const int j0 = blockIdx.x * 64;
  const int i0 = blockIdx.y * 64;
  const int sl = j0 >> 7;
  const int jjb = j0 & 127;
  if (i0 == 0 && tid < 64)
    WTS[(size_t)sl * SLICE_STRIDE + (size_t)NH * 128 + jjb + tid] = 0.0f;
#pragma unroll
  for (int k = 0; k < 16; ++k) {
    const int idx = k * 256 + tid;
    const int jl = idx >> 6, il = idx & 63;
    tile[jl][il] = Wrec[(size_t)(j0 + jl) * NH + i0 + il];
  }
  __syncthreads();
#pragma unroll
  for (int k = 0; k < 16; ++k) {
    const int idx = k * 256 + tid;
    const int il = idx >> 6, jl = idx & 63;
    WTS[(size_t)sl * SLICE_STRIDE + (size_t)(i0 + il) * 128 + jjb + jl] = tile[jl][il];
  }
}

// ---------------- kernel 2: I_ext = x @ W_in^T  (fp32 tiled) ----------------
// Kept fp32: bf16 I_ext would flip threshold crossings and cascade.
#define GBM 128
#define GBN 128
#define GBK 16
__global__ __launch_bounds__(256) void gemm_in(const float* __restrict__ X,
                                               const float* __restrict__ Win,
                                               float* __restrict__ I) {
  __shared__ float As[GBK][GBM + 4];
  __shared__ float Bs[GBK][GBN + 4];
  const int tid = threadIdx.x;
  const int m0 = blockIdx.x * GBM;
  const int n0 = blockIdx.y * GBN;
  const int tm = tid >> 4, tn = tid & 15;
  const int lr = tid >> 1, lk = (tid & 1) * 8;
  float acc[8][8] = {};
  for (int k0 = 0; k0 < NI; k0 += GBK) {
    float4 a0 = *(const float4*)&X[(size_t)(m0 + lr) * NI + k0 + lk];
    float4 a1 = *(const float4*)&X[(size_t)(m0 + lr) * NI + k0 + lk + 4];
    float4 b0 = *(const float4*)&Win[(size_t)(n0 + lr) * NI + k0 + lk];
    float4 b1 = *(const float4*)&Win[(size_t)(n0 + lr) * NI + k0 + lk + 4];
    As[lk + 0][lr] = a0.x; As[lk + 1][lr] = a0.y; As[lk + 2][lr] = a0.z; As[lk + 3][lr] = a0.w;
    As[lk + 4][lr] = a1.x; As[lk + 5][lr] = a1.y; As[lk + 6][lr] = a1.z; As[lk + 7][lr] = a1.w;
    Bs[lk + 0][lr] = b0.x; Bs[lk + 1][lr] = b0.y; Bs[lk + 2][lr] = b0.z; Bs[lk + 3][lr] = b0.w;
    Bs[lk + 4][lr] = b1.x; Bs[lk + 5][lr] = b1.y; Bs[lk + 6][lr] = b1.z; Bs[lk + 7][lr] = b1.w;
    __syncthreads();
#pragma unroll
    for (int k = 0; k < GBK; ++k) {
      float av[8], bv[8];
      *(float4*)&av[0] = *(const float4*)&As[k][tm * 8];
      *(float4*)&av[4] = *(const float4*)&As[k][tm * 8 + 4];
      *(float4*)&bv[0] = *(const float4*)&Bs[k][tn * 8];
      *(float4*)&bv[4] = *(const float4*)&Bs[k][tn * 8 + 4];
#pragma unroll
      for (int i2 = 0; i2 < 8; ++i2)
#pragma unroll
        for (int j2 = 0; j2 < 8; ++j2) acc[i2][j2] += av[i2] * bv[j2];
    }
    __syncthreads();
  }
#pragma unroll
  for (int i2 = 0; i2 < 8; ++i2) {
    float4 c0 = {acc[i2][0], acc[i2][1], acc[i2][2], acc[i2][3]};
    float4 c1 = {acc[i2][4], acc[i2][5], acc[i2][6], acc[i2][7]};
    *(float4*)&I[(size_t)(m0 + tm * 8 + i2) * NH + n0 + tn * 8] = c0;
    *(float4*)&I[(size_t)(m0 + tm * 8 + i2) * NH + n0 + tn * 8 + 4] = c1;
  }
}

// ---------------- kernel 3: persistent scan, per-chunk overlapped sync ----------
// 256 threads / 4 waves (one per SIMD -- no issue contention, unlike R7):
//   waves 0,1: neuron state + publish, then A-half gather (chunks 0-3, 1 col/thread),
//              then epf-spin + reduce.
//   wave 2:    poller; releases chunk q's flagq the moment its 4 words are fresh
//              (4-lane parallel expand, quad-shfl prefix). Early chunks gather
//              while stragglers are in flight.
//   wave 3:    B-half gather (chunks 4-7, 2 cols/thread float2), psumB, epf release.
// ALL handshake state parity-double-buffered (flagq/epf/psumB/slist). Skip-proof:
// flagq[par][q] advancing 2 epochs requires ALL producers to publish the next
// same-parity step, which requires THIS block's waves 0-1 to pass their reduce,
// which requires the spinning lane to have passed -- contradiction. Same argument
// for epf (via our publish in every chunk) and psumB/slist overwrite.
// FP order identical to R5-R7: per column, chunk-ascending/word-ascending/
// bit-ascending adds; pad entries read the zero row (+0.0f, exact no-op).
__global__ __launch_bounds__(256) void scan_rsnn(const float* __restrict__ Iext,
                                                 const float* __restrict__ WTS,
                                                 float* __restrict__ rate,
                                                 u64* sync) {
  __shared__ __align__(16) unsigned short slist[2][8 * SEG];
  __shared__ int flagq[2][8];     // (epoch<<8) | padded_cnt
  __shared__ int epf[2];          // psumB epoch
  __shared__ float psumB[2][128];

  const int bid = blockIdx.x;
  const int b   = bid >> 3;
  const int sl  = bid & 7;
  const int tid = threadIdx.x;
  const int wv  = tid >> 6;
  const int ln  = tid & 63;

  const float* wts = WTS + (size_t)sl * SLICE_STRIDE;

  const float D1 = 0.90483741803595957f;    // exp(-0.1)
  const float D2 = 0.81873075307798186f;    // exp(-0.2) == decay_syn

  if (tid < 16) flagq[tid >> 3][tid & 7] = 0;
  if (tid == 16) epf[0] = 0;
  if (tid == 17) epf[1] = 0;
  __syncthreads();                          // once, outside the loop

  float v = -60.0f, A1 = 0.0f, A2 = 0.0f, rf = 0.0f, h = 0.0f, psc = 0.0f;
  float ip = 0.0f;
  int sc = 0;
  if (tid < 128) ip = Iext[(size_t)b * NH + sl * 128 + tid];

#define LDW(slot, expr) w16[slot] = wts[(size_t)(expr) * 128 + tid];
#define LDF(slot, expr) f2[slot] = *(const float2*)&wts[(size_t)(expr) * 128 + j0c];

  for (int t = 0; t < T_STEPS; ++t) {
    const int par = t & 1;
    const int want = t + 1;
    u64* gbase = sync + ((size_t)(par * B_SZ + b)) * (NSLICE * 4);

    if (wv < 2) {
      // ---- state update (op order matches reference); publish ASAP ----
      const float I = ip + psc;
      A1 *= D1; A2 *= D2;
      v = v + ((-60.0f - v) / 20.0f + (I + A1 + A2) / 2.0f);
      const bool inref = rf > 0.0f;
      if (inref) v = -60.0f;
      const bool spike = (!inref) && (v >= -45.0f);
      const u64 bal = __ballot(spike);
      if (ln < 2) {
        const int w = wv * 2 + ln;          // word layout identical to R5-R7
        const unsigned payload = ln ? (unsigned)(bal >> 32) : (unsigned)bal;
        st64_agent(&gbase[sl * 4 + w], (u64)payload | ((u64)(unsigned)want << 32));
      }
      if (spike) { v = -60.0f; A1 += 1.0f; A2 += -2.0f; rf = 2.0f; sc++; }
      else       { rf = fmaxf(rf - 1.0f, 0.0f); }
      __builtin_amdgcn_sched_barrier(0);    // keep prefetch below the publish
      const int tn2 = (t + 1 < T_STEPS) ? t + 1 : t;
      ip = Iext[((size_t)tn2 * B_SZ + b) * NH + sl * 128 + tid];

      // ---- A-half gather: chunks 0..3 in order, as released ----
      float s = 0.0f;
#pragma unroll
      for (int q2 = 0; q2 < 4; ++q2) {
        int fv = ld_acq(&flagq[par][q2]);
        while ((fv >> 8) < want) fv = ld_acq(&flagq[par][q2]);
        const int cnt = fv & 255;           // padded to multiple of 16
        const unsigned short* sp = &slist[par][q2 * SEG];
        for (int k = 0; k < cnt; k += 16) {
          const uint4* ivp = (const uint4*)(&sp[k]);
          const uint4 a = ivp[0], c = ivp[1];
          float w16[16];
          LDW(0, a.x & 0xFFFFu) LDW(1, a.x >> 16) LDW(2, a.y & 0xFFFFu) LDW(3, a.y >> 16)
          LDW(4, a.z & 0xFFFFu) LDW(5, a.z >> 16) LDW(6, a.w & 0xFFFFu) LDW(7, a.w >> 16)
          LDW(8, c.x & 0xFFFFu) LDW(9, c.x >> 16) LDW(10, c.y & 0xFFFFu) LDW(11, c.y >> 16)
          LDW(12, c.z & 0xFFFFu) LDW(13, c.z >> 16) LDW(14, c.w & 0xFFFFu) LDW(15, c.w >> 16)
#pragma unroll
          for (int m2 = 0; m2 < 16; ++m2) s += w16[m2];   // in-order adds
        }
      }
      // ---- reduce ----
      {
        int e = ld_acq(&epf[par]);
        while (e < want) e = ld_acq(&epf[par]);
      }
      const float rec = s + psumB[par][tid];   // same A+B association as R2-R7
      h = D2 * h + rec;
      psc = D2 * psc + h;
    } else if (wv == 3) {
      // ---- B-half gather: chunks 4..7, columns 2ln, 2ln+1 ----
      const int j0c = 2 * ln;
      float s0 = 0.0f, s1 = 0.0f;
#pragma unroll
      for (int q2 = 4; q2 < 8; ++q2) {
        int fv = ld_acq(&flagq[par][q2]);
        while ((fv >> 8) < want) fv = ld_acq(&flagq[par][q2]);
        const int cnt = fv & 255;
        const unsigned short* sp = &slist[par][q2 * SEG];
        for (int k = 0; k < cnt; k += 16) {
          const uint4* ivp = (const uint4*)(&sp[k]);
          const uint4 a = ivp[0], c = ivp[1];
          float2 f2[16];
          LDF(0, a.x & 0xFFFFu) LDF(1, a.x >> 16) LDF(2, a.y & 0xFFFFu) LDF(3, a.y >> 16)
          LDF(4, a.z & 0xFFFFu) LDF(5, a.z >> 16) LDF(6, a.w & 0xFFFFu) LDF(7, a.w >> 16)
          LDF(8, c.x & 0xFFFFu) LDF(9, c.x >> 16) LDF(10, c.y & 0xFFFFu) LDF(11, c.y >> 16)
          LDF(12, c.z & 0xFFFFu) LDF(13, c.z >> 16) LDF(14, c.w & 0xFFFFu) LDF(15, c.w >> 16)
#pragma unroll
          for (int m2 = 0; m2 < 16; ++m2) { s0 += f2[m2].x; s1 += f2[m2].y; }
        }
      }
      psumB[par][j0c] = s0;
      psumB[par][j0c + 1] = s1;
      if (ln == 0) st_rel(&epf[par], want);   // release orders the wave's LDS writes
    } else {
      // ---- wave 2: poll all 32 words; release each chunk as it completes ----
      const int q = ln >> 2;
      const int r = ln & 3;
      const u64* gp = &gbase[ln];
      unsigned short* sbse = &slist[par][0];
      unsigned done = 0;
      while (done != 0xFFu) {
        u64 vwd = 0;
        bool fresh = false;
        if (ln < 32 && !((done >> q) & 1u)) {
          vwd = ld64_agent(gp);
          fresh = ((unsigned)(vwd >> 32) == (unsigned)want);
        }
        const u64 balf = __ballot(fresh);
        unsigned newly = 0;
#pragma unroll
        for (int qq = 0; qq < 8; ++qq)
          if (((balf >> (4 * qq)) & 0xFull) == 0xFull) newly |= (1u << qq);
        newly &= ~done;
        if (ln < 32 && ((newly >> q) & 1u)) {
          const unsigned myw = (unsigned)vwd;
          const int pc = __popc(myw);
          const int p0 = __shfl(pc, 4 * q + 0);
          const int p1 = __shfl(pc, 4 * q + 1);
          const int p2 = __shfl(pc, 4 * q + 2);
          const int p3 = __shfl(pc, 4 * q + 3);
          int off = ((r > 0) ? p0 : 0) + ((r > 1) ? p1 : 0) + ((r > 2) ? p2 : 0);
          const int cnt = p0 + p1 + p2 + p3;
          const int padded = (cnt + 15) & ~15;
          unsigned short* sp = sbse + q * SEG;
          unsigned m = myw;
          const int basei = q * 128 + r * 32;
          while (m) {
            const int bit = __builtin_ctz(m);
            m &= m - 1;
            sp[off++] = (unsigned short)(basei + bit);   // word/bit-ascending order
          }
          for (int z = cnt + r; z < padded; z += 4) sp[z] = (unsigned short)ZROW;
          if (r == 0) st_rel(&flagq[par][q], (want << 8) | padded);  // data precedes flag
        }
        done |= newly;
      }
    }
  }

  if (tid < 128) rate[(size_t)b * NH + sl * 128 + tid] = (float)sc / 1000.0f;
#undef LDW
#undef LDF
}

// ---------------- kernel 4: out = rate @ W_out^T ----------------
__global__ __launch_bounds__(256) void out_gemv(const float* __restrict__ rate,
                                                const float* __restrict__ Wout,
                                                float* __restrict__ out) {
  __shared__ float rs[NH];
  const int b = blockIdx.x, tid = threadIdx.x;
  for (int i = tid; i < NH; i += 256) rs[i] = rate[(size_t)b * NH + i];
  __syncthreads();
  const float* wr = Wout + (size_t)tid * NH;
  float s = 0.0f;
  for (int hh = 0; hh < NH; hh += 4) {
    float4 w4 = *(const float4*)&wr[hh];
    s += rs[hh] * w4.x + rs[hh + 1] * w4.y + rs[hh + 2] * w4.z + rs[hh + 3] * w4.w;
  }
  out[(size_t)b * NO + tid] = s;
}

// ---------------- launch ----------------
extern "C" void kernel_launch(void* const* d_in, const int* in_sizes, int n_in,
                              void* d_out, int out_size, void* d_ws, size_t ws_size,
                              hipStream_t stream) {
  const float* x    = (const float*)d_in[0];
  const float* Win  = (const float*)d_in[1];
  const float* Wrec = (const float*)d_in[2];
  const float* Wout = (const float*)d_in[3];
  float* out = (float*)d_out;

  char* ws = (char*)d_ws;
  float* Iext = (float*)(ws + OFF_IEXT);
  float* WTS  = (float*)(ws + OFF_WTS);
  float* rate = (float*)(ws + OFF_RATE);
  u64*   sync = (u64*)(ws + OFF_SYNC);
  // No memset needed: 0xAA poison tag (0xAAAAAAAA) never equals t+1 <= 1000,
  // and every block publishes before any of its spins -> no deadlock.

  prep_wts<<<dim3(16, 16), dim3(256), 0, stream>>>(Wrec, WTS);
  gemm_in<<<dim3((T_STEPS * B_SZ) / GBM, NH / GBN), dim3(256), 0, stream>>>(x, Win, Iext);
  scan_rsnn<<<dim3(NBLK), dim3(256), 0, stream>>>(Iext, WTS, rate, sync);
  out_gemv<<<dim3(B_SZ), dim3(256), 0, stream>>>(rate, Wout, out);
}

// Round 9
// 4185.987 us; speedup vs baseline: 1.2460x; 1.0026x over previous
//
#include <hip/hip_runtime.h>
#include <stdint.h>

// ---------------- problem constants ----------------
#define T_STEPS 1000
#define B_SZ    32
#define NI      512
#define NH      1024
#define NO      256

#define NSLICE  8     // neuron slices per batch; block (b,sl) owns 128 neurons of batch b
#define NBLK    (B_SZ * NSLICE)   // 256 scan blocks
#define SEGB    544   // B-half slist base (u16 units; 1088 B, 16B-aligned)
#define ZROW    1024  // per-slice zero row (pad entries add +0.0f, exact no-op)
#define SLICE_STRIDE ((NH + 1) * 128)   // floats per slice incl. zero row

typedef unsigned long long u64;

// ---------------- ws layout (bytes) ----------------
#define OFF_IEXT 0ull
#define SZ_IEXT  ((unsigned long long)T_STEPS * B_SZ * NH * 4ull)   // 131,072,000
#define OFF_WTS  (OFF_IEXT + SZ_IEXT)
#define SZ_WTS   ((unsigned long long)NSLICE * SLICE_STRIDE * 4ull) // 4,198,400
#define OFF_RATE (OFF_WTS + SZ_WTS)
#define SZ_RATE  ((unsigned long long)B_SZ * NH * 4ull)             // 128 KiB
#define OFF_RAILB (OFF_RATE + SZ_RATE)
#define SZ_RAIL  ((unsigned long long)2 * B_SZ * NSLICE * 4 * 8ull) // 16 KiB each
#define OFF_RAILA (OFF_RAILB + SZ_RAIL)

// ---------------- scope helpers ----------------
__device__ __forceinline__ u64 ld64_agent(const u64* p) {
  return __hip_atomic_load(p, __ATOMIC_RELAXED, __HIP_MEMORY_SCOPE_AGENT);
}
__device__ __forceinline__ void st64_agent(u64* p, u64 v) {
  __hip_atomic_store(p, v, __ATOMIC_RELAXED, __HIP_MEMORY_SCOPE_AGENT);
}
// Rail-A: L2-served ops (sc0 = bypass L1, served at the XCD's L2). Coherent
// only within an XCD -- used purely as a latency accelerator; rail-B (agent)
// guarantees correctness regardless of block->XCD placement (G16).
__device__ __forceinline__ u64 ld64_sc0(const u64* p) {
  u64 r;
  asm volatile("global_load_dwordx2 %0, %1, off sc0\n\ts_waitcnt vmcnt(0)"
               : "=v"(r) : "v"(p) : "memory");
  return r;
}
__device__ __forceinline__ void st64_sc0(u64* p, u64 v) {
  asm volatile("global_store_dwordx2 %0, %1, off sc0" :: "v"(p), "v"(v) : "memory");
}
// LDS epoch-tagged mask exchange (workgroup release/acquire)
__device__ __forceinline__ u64 ld64_acq_wg(const u64* p) {
  return __hip_atomic_load(p, __ATOMIC_ACQUIRE, __HIP_MEMORY_SCOPE_WORKGROUP);
}
__device__ __forceinline__ void st64_rel_wg(u64* p, u64 v) {
  __hip_atomic_store(p, v, __ATOMIC_RELEASE, __HIP_MEMORY_SCOPE_WORKGROUP);
}

// ---------------- kernel 1: transpose W_rec -> WTS (+ zero pad row) ------------
__global__ __launch_bounds__(256) void prep_wts(const float* __restrict__ Wrec,
                                                float* __restrict__ WTS) {
  __shared__ float tile[64][65];
  const int tid = threadIdx.x;
  const int j0 = blockIdx.x * 64;
  const int i0 = blockIdx.y * 64;
  const int sl = j0 >> 7;
  const int jjb = j0 & 127;
  if (i0 == 0 && tid < 64)
    WTS[(size_t)sl * SLICE_STRIDE + (size_t)NH * 128 + jjb + tid] = 0.0f;
#pragma unroll
  for (int k = 0; k < 16; ++k) {
    const int idx = k * 256 + tid;
    const int jl = idx >> 6, il = idx & 63;
    tile[jl][il] = Wrec[(size_t)(j0 + jl) * NH + i0 + il];
  }
  __syncthreads();
#pragma unroll
  for (int k = 0; k < 16; ++k) {
    const int idx = k * 256 + tid;
    const int il = idx >> 6, jl = idx & 63;
    WTS[(size_t)sl * SLICE_STRIDE + (size_t)(i0 + il) * 128 + jjb + jl] = tile[jl][il];
  }
}

// ---------------- kernel 2: I_ext = x @ W_in^T  (fp32 tiled) ----------------
// Kept fp32: bf16 I_ext would flip threshold crossings and cascade.
#define GBM 128
#define GBN 128
#define GBK 16
__global__ __launch_bounds__(256) void gemm_in(const float* __restrict__ X,
                                               const float* __restrict__ Win,
                                               float* __restrict__ I) {
  __shared__ float As[GBK][GBM + 4];
  __shared__ float Bs[GBK][GBN + 4];
  const int tid = threadIdx.x;
  const int m0 = blockIdx.x * GBM;
  const int n0 = blockIdx.y * GBN;
  const int tm = tid >> 4, tn = tid & 15;
  const int lr = tid >> 1, lk = (tid & 1) * 8;
  float acc[8][8] = {};
  for (int k0 = 0; k0 < NI; k0 += GBK) {
    float4 a0 = *(const float4*)&X[(size_t)(m0 + lr) * NI + k0 + lk];
    float4 a1 = *(const float4*)&X[(size_t)(m0 + lr) * NI + k0 + lk + 4];
    float4 b0 = *(const float4*)&Win[(size_t)(n0 + lr) * NI + k0 + lk];
    float4 b1 = *(const float4*)&Win[(size_t)(n0 + lr) * NI + k0 + lk + 4];
    As[lk + 0][lr] = a0.x; As[lk + 1][lr] = a0.y; As[lk + 2][lr] = a0.z; As[lk + 3][lr] = a0.w;
    As[lk + 4][lr] = a1.x; As[lk + 5][lr] = a1.y; As[lk + 6][lr] = a1.z; As[lk + 7][lr] = a1.w;
    Bs[lk + 0][lr] = b0.x; Bs[lk + 1][lr] = b0.y; Bs[lk + 2][lr] = b0.z; Bs[lk + 3][lr] = b0.w;
    Bs[lk + 4][lr] = b1.x; Bs[lk + 5][lr] = b1.y; Bs[lk + 6][lr] = b1.z; Bs[lk + 7][lr] = b1.w;
    __syncthreads();
#pragma unroll
    for (int k = 0; k < GBK; ++k) {
      float av[8], bv[8];
      *(float4*)&av[0] = *(const float4*)&As[k][tm * 8];
      *(float4*)&av[4] = *(const float4*)&As[k][tm * 8 + 4];
      *(float4*)&bv[0] = *(const float4*)&Bs[k][tn * 8];
      *(float4*)&bv[4] = *(const float4*)&Bs[k][tn * 8 + 4];
#pragma unroll
      for (int i2 = 0; i2 < 8; ++i2)
#pragma unroll
        for (int j2 = 0; j2 < 8; ++j2) acc[i2][j2] += av[i2] * bv[j2];
    }
    __syncthreads();
  }
#pragma unroll
  for (int i2 = 0; i2 < 8; ++i2) {
    float4 c0 = {acc[i2][0], acc[i2][1], acc[i2][2], acc[i2][3]};
    float4 c1 = {acc[i2][4], acc[i2][5], acc[i2][6], acc[i2][7]};
    *(float4*)&I[(size_t)(m0 + tm * 8 + i2) * NH + n0 + tn * 8] = c0;
    *(float4*)&I[(size_t)(m0 + tm * 8 + i2) * NH + n0 + tn * 8 + 4] = c1;
  }
}

// ---------------- kernel 3: persistent scan, dual-rail sync ----------------
// R6 skeleton (best measured): 4 waves, poll -> compact -> B1 -> gather -> B2
// -> reduce. New: bid = sl*32 + b so a batch-group's 8 blocks share bid%8 ->
// same XCD under round-robin dispatch. Producers publish each tagged word on
// rail-A (sc0/L2, fast iff co-XCD) AND rail-B (agent/MALL, always correct).
// Wave 3 polls rail-A, wave 2 polls rail-B; epoch-tagged fresh-masks exchanged
// via LDS release/acquire; each word completes from whichever rail is first.
// Wave 3 deposits its payloads in LDS bitmap; wave 2 compacts (register vals
// for its own detections, bitmap for wave-3-detected words). Identical-value
// LDS write races are benign (payloads are the same producer word).
__global__ __launch_bounds__(256) void scan_rsnn(const float* __restrict__ Iext,
                                                 const float* __restrict__ WTS,
                                                 float* __restrict__ rate,
                                                 u64* railB, u64* railA) {
  __shared__ __align__(16) unsigned short slist[2 * SEGB];  // A at 0, B at SEGB
  __shared__ unsigned bitmap[32];   // payloads deposited by wave 3 (rail-A)
  __shared__ u64 fmA, fmB;          // (epoch<<32) | fresh-mask
  __shared__ int scnt[2];           // padded counts
  __shared__ float psumB[128];

  const int bid = blockIdx.x;
  const int sl  = bid >> 5;          // slice: bid = sl*32 + b -> bid%8 == b%8
  const int b   = bid & 31;          // batch
  const int tid = threadIdx.x;
  const int wv  = tid >> 6;
  const int ln  = tid & 63;

  const float* wts = WTS + (size_t)sl * SLICE_STRIDE;

  const float D1 = 0.90483741803595957f;    // exp(-0.1)
  const float D2 = 0.81873075307798186f;    // exp(-0.2) == decay_syn

  if (tid == 0) fmA = 0;
  if (tid == 1) fmB = 0;
  __syncthreads();

  float v = -60.0f, A1 = 0.0f, A2 = 0.0f, rf = 0.0f, h = 0.0f, psc = 0.0f;
  float ip = 0.0f;
  int sc = 0;
  if (tid < 128) ip = Iext[(size_t)b * NH + sl * 128 + tid];

#define LDW(slot, expr) w16[slot] = wts[(size_t)(expr) * 128 + col];

  for (int t = 0; t < T_STEPS; ++t) {
    const int par = t & 1;
    const int want = t + 1;
    u64* gB = railB + ((size_t)(par * B_SZ + b)) * (NSLICE * 4);
    u64* gA = railA + ((size_t)(par * B_SZ + b)) * (NSLICE * 4);

    if (wv < 2) {
      // ---- state update (op order matches reference); publish both rails ----
      const float I = ip + psc;
      A1 *= D1; A2 *= D2;
      v = v + ((-60.0f - v) / 20.0f + (I + A1 + A2) / 2.0f);
      const bool inref = rf > 0.0f;
      if (inref) v = -60.0f;
      const bool spike = (!inref) && (v >= -45.0f);
      const u64 bal = __ballot(spike);
      if (ln < 4) {
        const int w = wv * 2 + (ln & 1);    // word layout identical to R5-R8
        const unsigned payload = (ln & 1) ? (unsigned)(bal >> 32) : (unsigned)bal;
        const u64 word = (u64)payload | ((u64)(unsigned)want << 32);
        if (ln < 2) st64_sc0(&gA[sl * 4 + w], word);     // fast rail first
        else        st64_agent(&gB[sl * 4 + w], word);   // guaranteed rail
      }
      if (spike) { v = -60.0f; A1 += 1.0f; A2 += -2.0f; rf = 2.0f; sc++; }
      else       { rf = fmaxf(rf - 1.0f, 0.0f); }
      __builtin_amdgcn_sched_barrier(0);    // keep prefetch below the publish
      const int tn2 = (t + 1 < T_STEPS) ? t + 1 : t;
      ip = Iext[((size_t)tn2 * B_SZ + b) * NH + sl * 128 + tid];
    } else if (wv == 2) {
      // ---- rail-B poller + compactor ----
      u64 val = 0; bool fresh = false;
      const u64* gp = &gB[ln & 31];
      unsigned um;
      for (;;) {
        if (ln < 32 && !fresh) {
          val = ld64_agent(gp);
          fresh = ((unsigned)(val >> 32) == (unsigned)want);
        }
        const unsigned mine = (unsigned)__ballot(fresh);
        if (ln == 0) st64_rel_wg(&fmB, ((u64)(unsigned)want << 32) | mine);
        const u64 oth = ld64_acq_wg(&fmA);
        const unsigned omask = ((unsigned)(oth >> 32) == (unsigned)want) ? (unsigned)oth : 0u;
        um = mine | omask;
        if (um == 0xFFFFFFFFu) break;
      }
      // payloads: own register if I detected it, else wave 3's LDS deposit
      unsigned myw = 0;
      if (ln < 32) myw = fresh ? (unsigned)val : bitmap[ln];
      // ---- compact: A = words 0-15 -> slist[0..], B = words 16-31 -> slist[SEGB..]
      int inc = __popc(myw);
#pragma unroll
      for (int d = 1; d < 32; d <<= 1) {
        int y = __shfl_up(inc, d);
        if ((ln & 63) >= d) inc += y;
      }
      const int tA = __shfl(inc, 15);
      const int tB = __shfl(inc, 31) - tA;
      if (ln < 32) {
        const bool isB = ln >= 16;
        int off = (isB ? SEGB : 0) + (inc - __popc(myw)) - (isB ? tA : 0);
        unsigned m = myw;
        const int bi = ln * 32;
        while (m) {
          const int bit = __builtin_ctz(m);
          m &= m - 1;
          slist[off++] = (unsigned short)(bi + bit);   // word/bit-ascending order
        }
        const int padA = (tA + 15) & ~15, padB = (tB + 15) & ~15;
        if (!isB) { const int z = tA + ln;        if (z < padA) slist[z] = (unsigned short)ZROW; }
        else      { const int z = tB + (ln - 16); if (z < padB) slist[SEGB + z] = (unsigned short)ZROW; }
        if (ln == 15) scnt[0] = padA;
        if (ln == 31) scnt[1] = padB;
      }
    } else {
      // ---- wave 3: rail-A (L2) poller; deposits payloads into LDS bitmap ----
      u64 val = 0; bool fresh = false;
      const u64* gp = &gA[ln & 31];
      for (;;) {
        bool newly = false;
        if (ln < 32 && !fresh) {
          val = ld64_sc0(gp);
          newly = ((unsigned)(val >> 32) == (unsigned)want);
          if (newly) { bitmap[ln] = (unsigned)val; fresh = true; }
        }
        const unsigned mine = (unsigned)__ballot(fresh);
        if (ln == 0) st64_rel_wg(&fmA, ((u64)(unsigned)want << 32) | mine);
        const u64 oth = ld64_acq_wg(&fmB);
        const unsigned omask = ((unsigned)(oth >> 32) == (unsigned)want) ? (unsigned)oth : 0u;
        if ((mine | omask) == 0xFFFFFFFFu) break;
      }
    }
    __syncthreads();   // B1: slist/scnt ready

    // ---- gather: all 256 threads; A-half tid<128, B-half tid>=128 ----
    float s = 0.0f;
    {
      const bool isA = tid < 128;
      const int col = tid & 127;
      const int cnt = scnt[isA ? 0 : 1];
      const unsigned short* sp = &slist[isA ? 0 : SEGB];
      for (int k = 0; k < cnt; k += 16) {
        const uint4* ivp = (const uint4*)(&sp[k]);
        const uint4 a = ivp[0], c = ivp[1];
        float w16[16];
        LDW(0, a.x & 0xFFFFu) LDW(1, a.x >> 16) LDW(2, a.y & 0xFFFFu) LDW(3, a.y >> 16)
        LDW(4, a.z & 0xFFFFu) LDW(5, a.z >> 16) LDW(6, a.w & 0xFFFFu) LDW(7, a.w >> 16)
        LDW(8, c.x & 0xFFFFu) LDW(9, c.x >> 16) LDW(10, c.y & 0xFFFFu) LDW(11, c.y >> 16)
        LDW(12, c.z & 0xFFFFu) LDW(13, c.z >> 16) LDW(14, c.w & 0xFFFFu) LDW(15, c.w >> 16)
#pragma unroll
        for (int m2 = 0; m2 < 16; ++m2) s += w16[m2];   // in-order adds
      }
    }
    if (tid >= 128) psumB[tid - 128] = s;
    __syncthreads();   // B2: psumB ready; also guards slist/bitmap overwrite

    if (tid < 128) {
      const float rec = s + psumB[tid];     // same A+B association as R2-R8
      h = D2 * h + rec;
      psc = D2 * psc + h;
    }
  }

  if (tid < 128) rate[(size_t)b * NH + sl * 128 + tid] = (float)sc / 1000.0f;
#undef LDW
}

// ---------------- kernel 4: out = rate @ W_out^T ----------------
__global__ __launch_bounds__(256) void out_gemv(const float* __restrict__ rate,
                                                const float* __restrict__ Wout,
                                                float* __restrict__ out) {
  __shared__ float rs[NH];
  const int b = blockIdx.x, tid = threadIdx.x;
  for (int i = tid; i < NH; i += 256) rs[i] = rate[(size_t)b * NH + i];
  __syncthreads();
  const float* wr = Wout + (size_t)tid * NH;
  float s = 0.0f;
  for (int hh = 0; hh < NH; hh += 4) {
    float4 w4 = *(const float4*)&wr[hh];
    s += rs[hh] * w4.x + rs[hh + 1] * w4.y + rs[hh + 2] * w4.z + rs[hh + 3] * w4.w;
  }
  out[(size_t)b * NO + tid] = s;
}

// ---------------- launch ----------------
extern "C" void kernel_launch(void* const* d_in, const int* in_sizes, int n_in,
                              void* d_out, int out_size, void* d_ws, size_t ws_size,
                              hipStream_t stream) {
  const float* x    = (const float*)d_in[0];
  const float* Win  = (const float*)d_in[1];
  const float* Wrec = (const float*)d_in[2];
  const float* Wout = (const float*)d_in[3];
  float* out = (float*)d_out;

  char* ws = (char*)d_ws;
  float* Iext = (float*)(ws + OFF_IEXT);
  float* WTS  = (float*)(ws + OFF_WTS);
  float* rate = (float*)(ws + OFF_RATE);
  u64*   railB = (u64*)(ws + OFF_RAILB);
  u64*   railA = (u64*)(ws + OFF_RAILA);
  // No memset needed: 0xAA poison tag (0xAAAAAAAA) never equals t+1 <= 1000 on
  // either rail, and every block publishes rail-B before any spin can block ->
  // no deadlock even if the XCD-placement heuristic is wrong (rail-B completes).

  prep_wts<<<dim3(16, 16), dim3(256), 0, stream>>>(Wrec, WTS);
  gemm_in<<<dim3((T_STEPS * B_SZ) / GBM, NH / GBN), dim3(256), 0, stream>>>(x, Win, Iext);
  scan_rsnn<<<dim3(NBLK), dim3(256), 0, stream>>>(Iext, WTS, rate, railB, railA);
  out_gemv<<<dim3(B_SZ), dim3(256), 0, stream>>>(rate, Wout, out);
}